// Round 1
// baseline (217939.771 us; speedup 1.0000x reference)
//
#include <hip/hip_runtime.h>
#include <math.h>

#define TT 8192
#define DD 1024
#define KK 2
#define NWG 256

// ---- coherent (cross-XCD) scalar access: agent-scope atomics bypass L1/L2 ----
__device__ __forceinline__ float cload(const float* p) {
  return __hip_atomic_load(const_cast<float*>(p), __ATOMIC_RELAXED, __HIP_MEMORY_SCOPE_AGENT);
}
__device__ __forceinline__ void cstore(float* p, float v) {
  __hip_atomic_store(p, v, __ATOMIC_RELAXED, __HIP_MEMORY_SCOPE_AGENT);
}

// Grid barrier: flag-array, parallel arrival, wave-0 polls. Correct because
// __syncthreads() drains vmcnt (data stores complete at coherence point)
// before the flag store issues, and poll-exit value-dependency orders the
// subsequent staged loads.
__device__ __forceinline__ void gbar(unsigned* flags, unsigned id) {
  __syncthreads();
  if (threadIdx.x == 0)
    __hip_atomic_store(&flags[blockIdx.x], id, __ATOMIC_RELAXED, __HIP_MEMORY_SCOPE_AGENT);
  if (threadIdx.x < 64) {
    for (;;) {
      bool ok = true;
#pragma unroll
      for (int q = 0; q < 4; ++q) {
        unsigned f = __hip_atomic_load(&flags[threadIdx.x + 64 * q], __ATOMIC_RELAXED,
                                       __HIP_MEMORY_SCOPE_AGENT);
        ok = ok && (f >= id);
      }
      if (__all((int)ok)) break;
      __builtin_amdgcn_s_sleep(1);
    }
  }
  __syncthreads();
}

// Persistent recurrent kernel: weights in registers, h/r broadcast via d_ws arena.
// WG wg: wave v owns pre-row (4*wg+v); wave v owns U-rows ur=2v+s (k=ur>>2, row 4*wg+(ur&3)).
__global__ __launch_bounds__(256, 1)
void crsd_seq(const float* __restrict__ pwx, const float* __restrict__ Wh,
              const float* __restrict__ Wr, const float* __restrict__ Uw,
              float* __restrict__ out, float* __restrict__ hbuf,
              float* __restrict__ rbuf, unsigned* __restrict__ flags) {
  const int wg = blockIdx.x, tid = threadIdx.x;
  const int wv = tid >> 6, ln = tid & 63;
  const int row = wg * 4 + wv;

  __shared__ __align__(16) float sh_h[DD];
  __shared__ __align__(16) float sh_r[KK * DD];

  // ---- load weight registers (once) ----
  float wh[16], wr0[16], wr1[16], uwr[2][16];
#pragma unroll
  for (int c = 0; c < 4; ++c) {
    const int j = 4 * ln + 256 * c;
    float4 a = *(const float4*)&Wh[(size_t)row * DD + j];
    wh[4*c+0]=a.x; wh[4*c+1]=a.y; wh[4*c+2]=a.z; wh[4*c+3]=a.w;
    float4 b0 = *(const float4*)&Wr[(size_t)row * DD + j];
    wr0[4*c+0]=b0.x; wr0[4*c+1]=b0.y; wr0[4*c+2]=b0.z; wr0[4*c+3]=b0.w;
    float4 b1 = *(const float4*)&Wr[(size_t)DD * DD + (size_t)row * DD + j];
    wr1[4*c+0]=b1.x; wr1[4*c+1]=b1.y; wr1[4*c+2]=b1.z; wr1[4*c+3]=b1.w;
  }
#pragma unroll
  for (int s = 0; s < 2; ++s) {
    const int ur = wv * 2 + s;
    const int k = ur >> 2, rr = ur & 3;
    const int gr = wg * 4 + rr;
#pragma unroll
    for (int c = 0; c < 4; ++c) {
      float4 u4 = *(const float4*)&Uw[(size_t)k * DD * DD + (size_t)gr * DD + 4 * ln + 256 * c];
      uwr[s][4*c+0]=u4.x; uwr[s][4*c+1]=u4.y; uwr[s][4*c+2]=u4.z; uwr[s][4*c+3]=u4.w;
    }
  }
  // h_{-1} = 0
#pragma unroll
  for (int q = 0; q < 4; ++q) sh_h[tid + 256 * q] = 0.f;

  for (int t = 0; t < TT; ++t) {
    const int cur = t & 1, prv = cur ^ 1;

    // ---- phase 1: stage r_{t-1}; pre = pwx + Wh h_{t-1} + Wr r_{t-1}; h_t = tanh ----
#pragma unroll
    for (int q = 0; q < 8; ++q) {
      const int idx = tid + 256 * q;
      sh_r[idx] = cload(&rbuf[prv * (KK * DD) + idx]);
    }
    const float pw = (ln == 0) ? pwx[(size_t)t * DD + row] : 0.f;
    __syncthreads();
    float acc = 0.f;
#pragma unroll
    for (int c = 0; c < 4; ++c) {
      const int j = 4 * ln + 256 * c;
      float4 hv = *(const float4*)&sh_h[j];
      float4 r0 = *(const float4*)&sh_r[j];
      float4 r1 = *(const float4*)&sh_r[DD + j];
      acc += wh[4*c+0]*hv.x + wh[4*c+1]*hv.y + wh[4*c+2]*hv.z + wh[4*c+3]*hv.w;
      acc += wr0[4*c+0]*r0.x + wr0[4*c+1]*r0.y + wr0[4*c+2]*r0.z + wr0[4*c+3]*r0.w;
      acc += wr1[4*c+0]*r1.x + wr1[4*c+1]*r1.y + wr1[4*c+2]*r1.z + wr1[4*c+3]*r1.w;
    }
#pragma unroll
    for (int off = 32; off; off >>= 1) acc += __shfl_xor(acc, off, 64);
    if (ln == 0) {
      const float hn = tanhf(acc + pw);
      cstore(&hbuf[cur * DD + row], hn);
      out[(size_t)t * DD + row] = hn;
    }
    gbar(flags, 2u * (unsigned)t + 1u);

    // ---- phase 2: stage h_t; g = tanh(U h_t); r_t = 0.9 r_{t-1} + 0.1 g ----
#pragma unroll
    for (int q = 0; q < 4; ++q) {
      const int idx = tid + 256 * q;
      sh_h[idx] = cload(&hbuf[cur * DD + idx]);
    }
    __syncthreads();
#pragma unroll
    for (int s = 0; s < 2; ++s) {
      float a = 0.f;
#pragma unroll
      for (int c = 0; c < 4; ++c) {
        const int j = 4 * ln + 256 * c;
        float4 hv = *(const float4*)&sh_h[j];
        a += uwr[s][4*c+0]*hv.x + uwr[s][4*c+1]*hv.y + uwr[s][4*c+2]*hv.z + uwr[s][4*c+3]*hv.w;
      }
#pragma unroll
      for (int off = 32; off; off >>= 1) a += __shfl_xor(a, off, 64);
      if (ln == 0) {
        const int ur = wv * 2 + s;
        const int k = ur >> 2;
        const int gr = wg * 4 + (ur & 3);
        const float rold = sh_r[k * DD + gr];
        const float rn = 0.9f * rold + 0.1f * tanhf(a);
        cstore(&rbuf[cur * (KK * DD) + k * DD + gr], rn);
      }
    }
    gbar(flags, 2u * (unsigned)t + 2u);
  }
}

// C[M][1024] = A[M][1024] @ W^T + bias   (W row-major [1024][1024])
__global__ __launch_bounds__(256)
void gemm_bias(const float* __restrict__ A, const float* __restrict__ W,
               const float* __restrict__ bias, float* __restrict__ C) {
  __shared__ float As[32][65];
  __shared__ float Ws[32][65];
  const int tid = threadIdx.x;
  const int bm = blockIdx.x * 64;
  const int bn = blockIdx.y * 64;
  const int ty = tid >> 4, tx = tid & 15;
  float acc[4][4] = {};
  for (int k0 = 0; k0 < DD; k0 += 32) {
#pragma unroll
    for (int p = 0; p < 2; ++p) {
      const int idx = tid + p * 256;       // 0..511
      const int r = idx >> 3;              // 0..63
      const int cf = idx & 7;              // float4 within the 32-wide K slab
      float4 av = *(const float4*)&A[(size_t)(bm + r) * DD + k0 + cf * 4];
      As[cf*4+0][r] = av.x; As[cf*4+1][r] = av.y; As[cf*4+2][r] = av.z; As[cf*4+3][r] = av.w;
      float4 wv = *(const float4*)&W[(size_t)(bn + r) * DD + k0 + cf * 4];
      Ws[cf*4+0][r] = wv.x; Ws[cf*4+1][r] = wv.y; Ws[cf*4+2][r] = wv.z; Ws[cf*4+3][r] = wv.w;
    }
    __syncthreads();
#pragma unroll
    for (int kk = 0; kk < 32; ++kk) {
      float a[4], w[4];
#pragma unroll
      for (int e = 0; e < 4; ++e) { a[e] = As[kk][ty * 4 + e]; w[e] = Ws[kk][tx * 4 + e]; }
#pragma unroll
      for (int i = 0; i < 4; ++i)
#pragma unroll
        for (int j = 0; j < 4; ++j) acc[i][j] += a[i] * w[j];
    }
    __syncthreads();
  }
#pragma unroll
  for (int i = 0; i < 4; ++i) {
    const int m = bm + ty * 4 + i;
#pragma unroll
    for (int j = 0; j < 4; ++j) {
      const int n = bn + tx * 4 + j;
      C[(size_t)m * DD + n] = acc[i][j] + bias[n];
    }
  }
}

extern "C" void kernel_launch(void* const* d_in, const int* in_sizes, int n_in,
                              void* d_out, int out_size, void* d_ws, size_t ws_size,
                              hipStream_t stream) {
  const float* x  = (const float*)d_in[0];
  const float* Wx = (const float*)d_in[1];
  const float* Wh = (const float*)d_in[2];
  const float* Wr = (const float*)d_in[3];
  const float* U  = (const float*)d_in[4];
  const float* b  = (const float*)d_in[5];
  float* out = (float*)d_out;

  float* pwx = (float*)d_ws;                       // [T][D] fp32 = 32 MB
  float* hbuf = pwx + (size_t)TT * DD;             // [2][D]
  float* rbuf = hbuf + 2 * DD;                     // [2][K][D]
  unsigned* flags = (unsigned*)(rbuf + 2 * KK * DD);  // [NWG]
  const size_t ctrl_bytes = (2 * DD + 2 * KK * DD) * sizeof(float) + NWG * sizeof(unsigned);

  const dim3 ggrid(TT / 64, DD / 64), gblk(256);

  for (int l = 0; l < 2; ++l) {
    const float* src = (l == 0) ? x : (const float*)out;
    hipMemsetAsync(hbuf, 0, ctrl_bytes, stream);
    hipLaunchKernelGGL(gemm_bias, ggrid, gblk, 0, stream,
                       src, Wx + (size_t)l * DD * DD, b + (size_t)l * DD, pwx);
    const float* whp = Wh + (size_t)l * DD * DD;
    const float* wrp = Wr + (size_t)l * KK * DD * DD;
    const float* uwp = U + (size_t)l * KK * DD * DD;
    const float* pwxc = pwx;
    float* outp = out;
    float* hb = hbuf;
    float* rb = rbuf;
    unsigned* fl = flags;
    void* args[] = { (void*)&pwxc, (void*)&whp, (void*)&wrp, (void*)&uwp,
                     (void*)&outp, (void*)&hb, (void*)&rb, (void*)&fl };
    hipLaunchCooperativeKernel((const void*)crsd_seq, dim3(NWG), dim3(256),
                               args, 0, stream);
  }
}

// Round 2
// 81109.894 us; speedup vs baseline: 2.6870x; 2.6870x over previous
//
#include <hip/hip_runtime.h>
#include <math.h>

#define TT 8192
#define DD 1024
#define NWG 256   // 128 WGs per layer
#define TPB 512   // 8 waves per WG

// ---- coherent (cross-XCD, L3-coherence-point) accesses via sc0 sc1 ----
__device__ __forceinline__ void cstore1(float* p, float v) {
  asm volatile("global_store_dword %0, %1, off sc0 sc1\n\ts_waitcnt vmcnt(0)"
               :: "v"(p), "v"(v) : "memory");
}
__device__ __forceinline__ float4 cload4(const float* p) {
  float4 r;
  asm volatile("global_load_dwordx4 %0, %1, off sc0 sc1\n\ts_waitcnt vmcnt(0)"
               : "=&v"(r) : "v"(p) : "memory");
  return r;
}
__device__ __forceinline__ void cload4x2(const float* p0, const float* p1,
                                         float4& a, float4& b) {
  asm volatile("global_load_dwordx4 %0, %2, off sc0 sc1\n\t"
               "global_load_dwordx4 %1, %3, off sc0 sc1\n\t"
               "s_waitcnt vmcnt(0)"
               : "=&v"(a), "=&v"(b) : "v"(p0), "v"(p1) : "memory");
}

// Grid barrier: monotonic counter, 8 cache-line-padded slices.
// Arrival: thread 0 atomicAdd (its stores already drained: asm stores wait
// vmcnt(0) internally; __syncthreads drains the rest). Release: lanes 0..7 of
// wave 0 poll one slice each; other waves wait at s_barrier.
__device__ __forceinline__ void gbar(unsigned* cnt, unsigned ep) {
  __syncthreads();
  if (threadIdx.x == 0)
    __hip_atomic_fetch_add(&cnt[(blockIdx.x & 7) << 4], 1u,
                           __ATOMIC_RELAXED, __HIP_MEMORY_SCOPE_AGENT);
  if (threadIdx.x < 64) {
    const unsigned tgt = ep * (NWG / 8);
    for (;;) {
      bool ok = true;
      if (threadIdx.x < 8)
        ok = (__hip_atomic_load(&cnt[threadIdx.x << 4], __ATOMIC_RELAXED,
                                __HIP_MEMORY_SCOPE_AGENT) >= tgt);
      if (__all((int)ok)) break;
      __builtin_amdgcn_s_sleep(1);
    }
  }
  __syncthreads();
}

// Persistent pipelined 2-layer recurrent kernel.
// WGs 0..127 = layer 1, WGs 128..255 = layer 2 (runs one step behind).
// Wave wv of WG wg7 owns pre-row (wg7*8+wv) and U-rows (k=0,row),(k=1,row).
// Arena (floats): h1[2][DD] | h2[2][DD] | r1[2][2*DD] | r2[2][2*DD]
__global__ __launch_bounds__(TPB, 2)
void crsd_seq(const float* __restrict__ pwx, const float* __restrict__ Wx,
              const float* __restrict__ Wh, const float* __restrict__ Wr,
              const float* __restrict__ Uw, const float* __restrict__ bias,
              float* __restrict__ out, float* __restrict__ arena,
              unsigned* __restrict__ cnt) {
  const int wg = blockIdx.x, tid = threadIdx.x;
  const int wv = tid >> 6, ln = tid & 63;
  const int layer = wg >> 7, wg7 = wg & 127;
  const int row = wg7 * 8 + wv;
  const size_t MS = (size_t)DD * DD;

  __shared__ __align__(16) float sh_x[DD];      // layer 2: h1 (its input)
  __shared__ __align__(16) float sh_h[DD];      // own-layer h
  __shared__ __align__(16) float sh_r[2 * DD];  // own-layer r

  float* h1b = arena;
  float* h2b = arena + 2 * DD;
  float* r1b = arena + 4 * DD;
  float* r2b = arena + 8 * DD;
  float* hX = layer ? h2b : h1b;
  float* rX = layer ? r2b : r1b;

  const float* Whp = Wh + (size_t)layer * MS;
  const float* Wrp = Wr + (size_t)layer * 2 * MS;
  const float* Up  = Uw + (size_t)layer * 2 * MS;

  // ---- one-time weight load into registers ----
  float wh[16], wr0[16], wr1[16], wx[16], uw[2][16];
#pragma unroll
  for (int c = 0; c < 4; ++c) {
    const int j = 4 * ln + 256 * c;
    float4 a = *(const float4*)&Whp[(size_t)row * DD + j];
    wh[4*c+0]=a.x; wh[4*c+1]=a.y; wh[4*c+2]=a.z; wh[4*c+3]=a.w;
    float4 b0 = *(const float4*)&Wrp[(size_t)row * DD + j];
    wr0[4*c+0]=b0.x; wr0[4*c+1]=b0.y; wr0[4*c+2]=b0.z; wr0[4*c+3]=b0.w;
    float4 b1 = *(const float4*)&Wrp[MS + (size_t)row * DD + j];
    wr1[4*c+0]=b1.x; wr1[4*c+1]=b1.y; wr1[4*c+2]=b1.z; wr1[4*c+3]=b1.w;
    if (layer) {
      float4 xw = *(const float4*)&Wx[MS + (size_t)row * DD + j];
      wx[4*c+0]=xw.x; wx[4*c+1]=xw.y; wx[4*c+2]=xw.z; wx[4*c+3]=xw.w;
    } else {
      wx[4*c+0]=0.f; wx[4*c+1]=0.f; wx[4*c+2]=0.f; wx[4*c+3]=0.f;
    }
#pragma unroll
    for (int s2 = 0; s2 < 2; ++s2) {
      float4 u4 = *(const float4*)&Up[(size_t)s2 * MS + (size_t)row * DD + j];
      uw[s2][4*c+0]=u4.x; uw[s2][4*c+1]=u4.y; uw[s2][4*c+2]=u4.z; uw[s2][4*c+3]=u4.w;
    }
  }
  const float bb = layer ? bias[DD + row] : 0.f;
  float rown[2] = {0.f, 0.f};   // owned r rows (live in lane 0)

  for (int s = 0; s <= TT; ++s) {
    const int cur = s & 1, prv = cur ^ 1;
    const bool act = layer ? (s >= 1) : (s < TT);

    // ---- phase A: stage prev-parity state, compute h row ----
    if (act) {
      if (layer == 0) {
        if (tid < 256) {
          float4 a, b4;
          cload4x2(h1b + prv * DD + 4 * tid, r1b + prv * 2 * DD + 4 * tid, a, b4);
          *(float4*)&sh_h[4 * tid] = a;
          *(float4*)&sh_r[4 * tid] = b4;
        } else {
          *(float4*)&sh_r[4 * tid] = cload4(r1b + prv * 2 * DD + 4 * tid);
        }
      } else {
        if (tid < 256) {
          float4 a, b4;
          cload4x2(h1b + prv * DD + 4 * tid, h2b + prv * DD + 4 * tid, a, b4);
          *(float4*)&sh_x[4 * tid] = a;
          *(float4*)&sh_h[4 * tid] = b4;
        } else {
          const int e = 4 * tid - 1024;  // 0..1020
          float4 a, b4;
          cload4x2(r2b + prv * 2 * DD + e, r2b + prv * 2 * DD + e + 1024, a, b4);
          *(float4*)&sh_r[e] = a;
          *(float4*)&sh_r[e + 1024] = b4;
        }
      }
    }
    __syncthreads();
    if (act) {
      float acc = 0.f;
#pragma unroll
      for (int c = 0; c < 4; ++c) {
        const int j = 4 * ln + 256 * c;
        const float4 hv = *(const float4*)&sh_h[j];
        const float4 r0 = *(const float4*)&sh_r[j];
        const float4 r1v = *(const float4*)&sh_r[DD + j];
        acc += wh[4*c+0]*hv.x + wh[4*c+1]*hv.y + wh[4*c+2]*hv.z + wh[4*c+3]*hv.w
             + wr0[4*c+0]*r0.x + wr0[4*c+1]*r0.y + wr0[4*c+2]*r0.z + wr0[4*c+3]*r0.w
             + wr1[4*c+0]*r1v.x + wr1[4*c+1]*r1v.y + wr1[4*c+2]*r1v.z + wr1[4*c+3]*r1v.w;
        if (layer) {
          const float4 xv = *(const float4*)&sh_x[j];
          acc += wx[4*c+0]*xv.x + wx[4*c+1]*xv.y + wx[4*c+2]*xv.z + wx[4*c+3]*xv.w;
        }
      }
#pragma unroll
      for (int off = 32; off; off >>= 1) acc += __shfl_xor(acc, off, 64);
      if (ln == 0) {
        const float pre = acc + (layer ? bb : pwx[(size_t)s * DD + row]);
        const float hn = tanhf(pre);
        cstore1(hX + cur * DD + row, hn);
        if (layer) out[(size_t)(s - 1) * DD + row] = hn;
      }
    }
    if (s == TT) break;           // last slot: layer-2 wrote out[T-1]; done
    gbar(cnt, 2u * (unsigned)s + 1u);

    // ---- phase B: stage own-layer h (cur), update owned r rows ----
    if (act && tid < 256)
      *(float4*)&sh_h[4 * tid] = cload4(hX + cur * DD + 4 * tid);
    __syncthreads();
    if (act) {
#pragma unroll
      for (int s2 = 0; s2 < 2; ++s2) {
        float a = 0.f;
#pragma unroll
        for (int c = 0; c < 4; ++c) {
          const int j = 4 * ln + 256 * c;
          const float4 hv = *(const float4*)&sh_h[j];
          a += uw[s2][4*c+0]*hv.x + uw[s2][4*c+1]*hv.y
             + uw[s2][4*c+2]*hv.z + uw[s2][4*c+3]*hv.w;
        }
#pragma unroll
        for (int off = 32; off; off >>= 1) a += __shfl_xor(a, off, 64);
        if (ln == 0) {
          rown[s2] = 0.9f * rown[s2] + 0.1f * tanhf(a);
          cstore1(rX + cur * 2 * DD + s2 * DD + row, rown[s2]);
        }
      }
    }
    gbar(cnt, 2u * (unsigned)s + 2u);
  }
}

// C[M][1024] = A[M][1024] @ W^T + bias   (W row-major [1024][1024])
__global__ __launch_bounds__(256)
void gemm_bias(const float* __restrict__ A, const float* __restrict__ W,
               const float* __restrict__ bias, float* __restrict__ C) {
  __shared__ float As[32][65];
  __shared__ float Ws[32][65];
  const int tid = threadIdx.x;
  const int bm = blockIdx.x * 64;
  const int bn = blockIdx.y * 64;
  const int ty = tid >> 4, tx = tid & 15;
  float acc[4][4] = {};
  for (int k0 = 0; k0 < DD; k0 += 32) {
#pragma unroll
    for (int p = 0; p < 2; ++p) {
      const int idx = tid + p * 256;
      const int r = idx >> 3;
      const int cf = idx & 7;
      float4 av = *(const float4*)&A[(size_t)(bm + r) * DD + k0 + cf * 4];
      As[cf*4+0][r] = av.x; As[cf*4+1][r] = av.y; As[cf*4+2][r] = av.z; As[cf*4+3][r] = av.w;
      float4 wv = *(const float4*)&W[(size_t)(bn + r) * DD + k0 + cf * 4];
      Ws[cf*4+0][r] = wv.x; Ws[cf*4+1][r] = wv.y; Ws[cf*4+2][r] = wv.z; Ws[cf*4+3][r] = wv.w;
    }
    __syncthreads();
#pragma unroll
    for (int kk = 0; kk < 32; ++kk) {
      float a[4], w[4];
#pragma unroll
      for (int e = 0; e < 4; ++e) { a[e] = As[kk][ty * 4 + e]; w[e] = Ws[kk][tx * 4 + e]; }
#pragma unroll
      for (int i = 0; i < 4; ++i)
#pragma unroll
        for (int j = 0; j < 4; ++j) acc[i][j] += a[i] * w[j];
    }
    __syncthreads();
  }
#pragma unroll
  for (int i = 0; i < 4; ++i) {
    const int m = bm + ty * 4 + i;
#pragma unroll
    for (int j = 0; j < 4; ++j) {
      const int n = bn + tx * 4 + j;
      C[(size_t)m * DD + n] = acc[i][j] + bias[n];
    }
  }
}

extern "C" void kernel_launch(void* const* d_in, const int* in_sizes, int n_in,
                              void* d_out, int out_size, void* d_ws, size_t ws_size,
                              hipStream_t stream) {
  const float* x  = (const float*)d_in[0];
  const float* Wx = (const float*)d_in[1];
  const float* Wh = (const float*)d_in[2];
  const float* Wr = (const float*)d_in[3];
  const float* U  = (const float*)d_in[4];
  const float* b  = (const float*)d_in[5];
  float* out = (float*)d_out;

  float* pwx = (float*)d_ws;                    // [T][D] fp32 = 32 MB
  float* arena = pwx + (size_t)TT * DD;         // 12*DD floats = 48 KB
  unsigned* cnt = (unsigned*)(arena + 12 * DD); // 8 slices x 16 u32
  const size_t zero_bytes = 12 * DD * sizeof(float) + 8 * 16 * sizeof(unsigned);

  hipMemsetAsync(arena, 0, zero_bytes, stream);
  hipLaunchKernelGGL(gemm_bias, dim3(TT / 64, DD / 64), dim3(256), 0, stream,
                     x, Wx, b, pwx);  // layer-1 pwx = x @ Wx1^T + b1

  const float* pwxc = pwx;
  float* arenap = arena;
  unsigned* cntp = cnt;
  void* args[] = { (void*)&pwxc, (void*)&Wx, (void*)&Wh, (void*)&Wr,
                   (void*)&U, (void*)&b, (void*)&out, (void*)&arenap, (void*)&cntp };
  hipLaunchCooperativeKernel((const void*)crsd_seq, dim3(NWG), dim3(TPB),
                             args, 0, stream);
}

// Round 3
// 72654.669 us; speedup vs baseline: 2.9997x; 1.1164x over previous
//
#include <hip/hip_runtime.h>
#include <math.h>

#define TT 8192
#define DD 1024
#define NWG 256   // 128 WGs layer-1, 128 WGs layer-2
#define TPB 512   // 8 waves
#define SENT 2.0f
#define GCAP (1 << 20)

// ---- coherent (cross-XCD) ops: sc0 sc1 bypass L1/L2, serviced at fabric/LLC ----
__device__ __forceinline__ void cstore_nd(float* p, float v) {
  asm volatile("global_store_dword %0, %1, off sc0 sc1" :: "v"(p), "v"(v) : "memory");
}
__device__ __forceinline__ void vdrain() { asm volatile("s_waitcnt vmcnt(0)" ::: "memory"); }
__device__ __forceinline__ void cstore1(float* p, float v) { cstore_nd(p, v); vdrain(); }
__device__ __forceinline__ float4 cload4(const float* p) {
  float4 r;
  asm volatile("global_load_dwordx4 %0, %1, off sc0 sc1\n\ts_waitcnt vmcnt(0)"
               : "=&v"(r) : "v"(p) : "memory");
  return r;
}
// Poll until no element equals the sentinel. Capped: protocol bug -> wrong
// answer, never a hang.
__device__ __forceinline__ float4 pollload(const float* p) {
  float4 v = cload4(p);
  int g = 0;
  while ((v.x == SENT || v.y == SENT || v.z == SENT || v.w == SENT) && ++g < GCAP)
    v = cload4(p);
  return v;
}

// Arena (floats): h1s[8*DD] | h2s[8*DD] | r1s[8*2*DD] | r2s[8*2*DD]  (48*DD total)
__global__ void init_arena(float* __restrict__ arena, int* __restrict__ stamps) {
  const int idx = blockIdx.x * 256 + threadIdx.x;  // grid covers 48*DD
  float v = SENT;
  // slot 7 of each stream holds the step -1 state: zeros (pre-published).
  if ((idx >= 7 * DD && idx < 8 * DD) ||        // h1 slot 7
      (idx >= 15 * DD && idx < 16 * DD) ||      // h2 slot 7
      (idx >= 30 * DD && idx < 32 * DD) ||      // r1 slot 7
      (idx >= 46 * DD && idx < 48 * DD))        // r2 slot 7
    v = 0.f;
  arena[idx] = v;
  if (blockIdx.x == 0 && threadIdx.x < NWG) stamps[threadIdx.x] = -1;
}

// Persistent dataflow 2-layer CRSD. WGs 0..127: layer 1 (tick t = its step t);
// WGs 128..255: layer 2 (tick t = its step t, consumes h1_t as input).
// Wave wv of wg7 owns pre-row row=wg7*8+wv and U/r rows (k=0,row),(k=1,row).
__global__ __launch_bounds__(TPB, 2)
void crsd_seq(const float* __restrict__ pwx, const float* __restrict__ Wx,
              const float* __restrict__ Wh, const float* __restrict__ Wr,
              const float* __restrict__ Uw, const float* __restrict__ bias,
              float* __restrict__ out, float* __restrict__ arena,
              int* __restrict__ stamps) {
  const int wg = blockIdx.x, tid = threadIdx.x;
  const int wv = tid >> 6, ln = tid & 63;
  const int layer = wg >> 7, wg7 = wg & 127;
  const int row = wg7 * 8 + wv;
  const size_t MS = (size_t)DD * DD;

  float* h1s = arena;
  float* h2s = arena + 8 * DD;
  float* r1s = arena + 16 * DD;
  float* r2s = arena + 32 * DD;
  float* hS = layer ? h2s : h1s;
  float* rS = layer ? r2s : r1s;

  __shared__ __align__(16) float sh_x[DD];
  __shared__ __align__(16) float sh_h[DD];
  __shared__ __align__(16) float sh_r[2 * DD];

  const float* Whp = Wh + (size_t)layer * MS;
  const float* Wrp = Wr + (size_t)layer * 2 * MS;
  const float* Up  = Uw + (size_t)layer * 2 * MS;

  // ---- one-time weight load into registers ----
  float wh[16], wr0[16], wr1[16], wx[16], uw[2][16];
#pragma unroll
  for (int c = 0; c < 4; ++c) {
    const int j = 4 * ln + 256 * c;
    float4 a = *(const float4*)&Whp[(size_t)row * DD + j];
    wh[4*c+0]=a.x; wh[4*c+1]=a.y; wh[4*c+2]=a.z; wh[4*c+3]=a.w;
    float4 b0 = *(const float4*)&Wrp[(size_t)row * DD + j];
    wr0[4*c+0]=b0.x; wr0[4*c+1]=b0.y; wr0[4*c+2]=b0.z; wr0[4*c+3]=b0.w;
    float4 b1 = *(const float4*)&Wrp[MS + (size_t)row * DD + j];
    wr1[4*c+0]=b1.x; wr1[4*c+1]=b1.y; wr1[4*c+2]=b1.z; wr1[4*c+3]=b1.w;
    if (layer) {
      float4 xw = *(const float4*)&Wx[MS + (size_t)row * DD + j];
      wx[4*c+0]=xw.x; wx[4*c+1]=xw.y; wx[4*c+2]=xw.z; wx[4*c+3]=xw.w;
    } else {
      wx[4*c+0]=0.f; wx[4*c+1]=0.f; wx[4*c+2]=0.f; wx[4*c+3]=0.f;
    }
#pragma unroll
    for (int s2 = 0; s2 < 2; ++s2) {
      float4 u4 = *(const float4*)&Up[(size_t)s2 * MS + (size_t)row * DD + j];
      uw[s2][4*c+0]=u4.x; uw[s2][4*c+1]=u4.y; uw[s2][4*c+2]=u4.z; uw[s2][4*c+3]=u4.w;
    }
  }
  const float bb = layer ? bias[DD + row] : 0.f;
  float rown[2] = {0.f, 0.f};

  for (int t = 0; t < TT; ++t) {
    const int pv = (t - 1) & 7;   // previous-state slot ((-1)&7 == 7: init zeros)
    const int cu = t & 7;

    // ---- phase A: poll prev state into LDS (freshness guaranteed by gate(t-1)) ----
    if (tid < 256) {
      // own-layer h_{t-1} first (published mid-prev-tick: usually present)
      *(float4*)&sh_h[4 * tid] = pollload(hS + pv * DD + 4 * tid);
      if (layer)  // layer-2 input x = h1_t (the frontier: published mid-L1-tick t)
        *(float4*)&sh_x[4 * tid] = pollload(h1s + cu * DD + 4 * tid);
    }
    // r_{t-1}: all 512 threads (published at end of prev tick: the serial frontier)
    *(float4*)&sh_r[4 * tid] = pollload(rS + pv * 2 * DD + 4 * tid);
    const float pw = (!layer && ln == 0) ? pwx[(size_t)t * DD + row] : 0.f;
    __syncthreads();

    float acc = 0.f;
#pragma unroll
    for (int c = 0; c < 4; ++c) {
      const int j = 4 * ln + 256 * c;
      const float4 hv = *(const float4*)&sh_h[j];
      const float4 r0 = *(const float4*)&sh_r[j];
      const float4 r1v = *(const float4*)&sh_r[DD + j];
      acc += wh[4*c+0]*hv.x + wh[4*c+1]*hv.y + wh[4*c+2]*hv.z + wh[4*c+3]*hv.w
           + wr0[4*c+0]*r0.x + wr0[4*c+1]*r0.y + wr0[4*c+2]*r0.z + wr0[4*c+3]*r0.w
           + wr1[4*c+0]*r1v.x + wr1[4*c+1]*r1v.y + wr1[4*c+2]*r1v.z + wr1[4*c+3]*r1v.w;
      if (layer) {
        const float4 xv = *(const float4*)&sh_x[j];
        acc += wx[4*c+0]*xv.x + wx[4*c+1]*xv.y + wx[4*c+2]*xv.z + wx[4*c+3]*xv.w;
      }
    }
#pragma unroll
    for (int off = 32; off; off >>= 1) acc += __shfl_xor(acc, off, 64);
    if (ln == 0) {
      const float hn = tanhf(acc + (layer ? bb : pw));
      cstore1(hS + cu * DD + row, hn);
      if (layer) out[(size_t)t * DD + row] = hn;
    }

    // ---- gate zone: waves 1..4 poll h_t; wave 0 runs the lagged stamp gate ----
    __syncthreads();   // sh_h consumers done; h publishes issued
    if (wv >= 1 && wv <= 4) {
      const int j = tid - 64;  // 0..255
      *(float4*)&sh_h[4 * j] = pollload(hS + cu * DD + 4 * j);
    } else if (wv == 0 && t >= 3) {
      const int need = t - 3;
      int g = 0;
      for (;;) {
        const int i4 = 4 * ln;
        int s0 = __hip_atomic_load(&stamps[i4+0], __ATOMIC_RELAXED, __HIP_MEMORY_SCOPE_AGENT);
        int s1 = __hip_atomic_load(&stamps[i4+1], __ATOMIC_RELAXED, __HIP_MEMORY_SCOPE_AGENT);
        int s2 = __hip_atomic_load(&stamps[i4+2], __ATOMIC_RELAXED, __HIP_MEMORY_SCOPE_AGENT);
        int s3 = __hip_atomic_load(&stamps[i4+3], __ATOMIC_RELAXED, __HIP_MEMORY_SCOPE_AGENT);
        bool ok = (s0 >= need) && (s1 >= need) && (s2 >= need) && (s3 >= need);
        if (__all((int)ok)) break;
        if (++g > GCAP) break;
        __builtin_amdgcn_s_sleep(2);
      }
    }
    __syncthreads();
    // poison slot (t-4)&7 (its readers all finished tick t-3 per the gate)
    if (t >= 3 && ln == 0) {
      const int ps = (t - 4) & 7;
      cstore_nd(hS + ps * DD + row, SENT);
      cstore_nd(rS + ps * 2 * DD + row, SENT);
      cstore_nd(rS + ps * 2 * DD + DD + row, SENT);
      vdrain();
    }

    // ---- phase B: r update from full h_t ----
#pragma unroll
    for (int s2 = 0; s2 < 2; ++s2) {
      float a = 0.f;
#pragma unroll
      for (int c = 0; c < 4; ++c) {
        const int j = 4 * ln + 256 * c;
        const float4 hv = *(const float4*)&sh_h[j];
        a += uw[s2][4*c+0]*hv.x + uw[s2][4*c+1]*hv.y
           + uw[s2][4*c+2]*hv.z + uw[s2][4*c+3]*hv.w;
      }
#pragma unroll
      for (int off = 32; off; off >>= 1) a += __shfl_xor(a, off, 64);
      if (ln == 0) {
        rown[s2] = 0.9f * rown[s2] + 0.1f * tanhf(a);
        cstore_nd(rS + cu * 2 * DD + s2 * DD + row, rown[s2]);
      }
    }
    if (ln == 0) vdrain();   // all this wave's tick-t stores at coherence point
    __syncthreads();         // every wave's stores drained
    if (tid == 0)
      __hip_atomic_store(&stamps[wg], t, __ATOMIC_RELAXED, __HIP_MEMORY_SCOPE_AGENT);
  }
}

// C[M][1024] = A[M][1024] @ W^T + bias   (W row-major [1024][1024])
__global__ __launch_bounds__(256)
void gemm_bias(const float* __restrict__ A, const float* __restrict__ W,
               const float* __restrict__ bias, float* __restrict__ C) {
  __shared__ float As[32][65];
  __shared__ float Ws[32][65];
  const int tid = threadIdx.x;
  const int bm = blockIdx.x * 64;
  const int bn = blockIdx.y * 64;
  const int ty = tid >> 4, tx = tid & 15;
  float acc[4][4] = {};
  for (int k0 = 0; k0 < DD; k0 += 32) {
#pragma unroll
    for (int p = 0; p < 2; ++p) {
      const int idx = tid + p * 256;
      const int r = idx >> 3;
      const int cf = idx & 7;
      float4 av = *(const float4*)&A[(size_t)(bm + r) * DD + k0 + cf * 4];
      As[cf*4+0][r] = av.x; As[cf*4+1][r] = av.y; As[cf*4+2][r] = av.z; As[cf*4+3][r] = av.w;
      float4 wv = *(const float4*)&W[(size_t)(bn + r) * DD + k0 + cf * 4];
      Ws[cf*4+0][r] = wv.x; Ws[cf*4+1][r] = wv.y; Ws[cf*4+2][r] = wv.z; Ws[cf*4+3][r] = wv.w;
    }
    __syncthreads();
#pragma unroll
    for (int kk = 0; kk < 32; ++kk) {
      float a[4], w[4];
#pragma unroll
      for (int e = 0; e < 4; ++e) { a[e] = As[kk][ty * 4 + e]; w[e] = Ws[kk][tx * 4 + e]; }
#pragma unroll
      for (int i = 0; i < 4; ++i)
#pragma unroll
        for (int j = 0; j < 4; ++j) acc[i][j] += a[i] * w[j];
    }
    __syncthreads();
  }
#pragma unroll
  for (int i = 0; i < 4; ++i) {
    const int m = bm + ty * 4 + i;
#pragma unroll
    for (int j = 0; j < 4; ++j) {
      const int n = bn + tx * 4 + j;
      C[(size_t)m * DD + n] = acc[i][j] + bias[n];
    }
  }
}

extern "C" void kernel_launch(void* const* d_in, const int* in_sizes, int n_in,
                              void* d_out, int out_size, void* d_ws, size_t ws_size,
                              hipStream_t stream) {
  const float* x  = (const float*)d_in[0];
  const float* Wx = (const float*)d_in[1];
  const float* Wh = (const float*)d_in[2];
  const float* Wr = (const float*)d_in[3];
  const float* U  = (const float*)d_in[4];
  const float* b  = (const float*)d_in[5];
  float* out = (float*)d_out;

  float* pwx = (float*)d_ws;                 // [T][D] fp32 = 32 MB
  float* arena = pwx + (size_t)TT * DD;      // 48*DD floats
  int* stamps = (int*)(arena + 48 * DD);     // NWG ints

  hipLaunchKernelGGL(init_arena, dim3(48 * DD / 256), dim3(256), 0, stream,
                     arena, stamps);
  hipLaunchKernelGGL(gemm_bias, dim3(TT / 64, DD / 64), dim3(256), 0, stream,
                     x, Wx, b, pwx);  // layer-1 pwx = x @ Wx1^T + b1

  const float* pwxc = pwx;
  float* arenap = arena;
  int* stampsp = stamps;
  void* args[] = { (void*)&pwxc, (void*)&Wx, (void*)&Wh, (void*)&Wr,
                   (void*)&U, (void*)&b, (void*)&out, (void*)&arenap, (void*)&stampsp };
  hipLaunchCooperativeKernel((const void*)crsd_seq, dim3(NWG), dim3(TPB),
                             args, 0, stream);
}